// Round 1
// baseline (798.470 us; speedup 1.0000x reference)
//
#include <hip/hip_runtime.h>
#include <hip/hip_bf16.h>
#include <math.h>

// Problem constants (B=2, I=8, J=1025, M=256, H=8, Dh=32)
#define BB   2
#define II   8
#define JJ   1025
#define MM   256
#define HH   8
#define DH   32
#define BI   (BB*II)          // 16
#define RTOT (BI*JJ)          // 16400 rows (tokens)
#define NQKV (3*MM)           // 768
#define HID  (4*MM)           // 1024

// ---------------------------------------------------------------------------
// K0: row sums of Wo -> woSum[256]
// ---------------------------------------------------------------------------
__global__ void k_wosum(const float* __restrict__ Wo, float* __restrict__ woSum) {
    int m = threadIdx.x;
    float s = 0.f;
    for (int n = 0; n < MM; ++n) s += Wo[m * MM + n];
    woSum[m] = s;
}

// ---------------------------------------------------------------------------
// K1/K5: per-row LayerNorm stats (mu, rstd) for a [R x 256] fp32 tensor
// ---------------------------------------------------------------------------
__global__ __launch_bounds__(256) void k_lnstats(const float* __restrict__ src,
                                                 float2* __restrict__ stats) {
    __shared__ float red[256];
    int r = blockIdx.x;
    int t = threadIdx.x;
    float x = src[(size_t)r * MM + t];

    red[t] = x;
    __syncthreads();
    for (int s = 128; s > 0; s >>= 1) {
        if (t < s) red[t] += red[t + s];
        __syncthreads();
    }
    float mu = red[0] * (1.0f / MM);
    __syncthreads();

    float d = x - mu;
    red[t] = d * d;
    __syncthreads();
    for (int s = 128; s > 0; s >>= 1) {
        if (t < s) red[t] += red[t + s];
        __syncthreads();
    }
    if (t == 0) {
        float var = red[0] * (1.0f / MM);
        stats[r] = make_float2(mu, 1.0f / sqrtf(var + 1e-5f));
    }
}

// ---------------------------------------------------------------------------
// Tiled fp32 GEMM: C[r][n] = epilogue( sum_k A'[r][k] * W[n][k] )
//   A' = LN_A ? (A-mu)*rstd*gamma+beta : A
//   epilogue: (+bias[n]) -> (gelu) -> (+addsrc[r][n])
// BM=BN=64, BK=16, 256 threads, 4x4 per thread.
// ---------------------------------------------------------------------------
__device__ __forceinline__ float gelu_exact(float x) {
    return 0.5f * x * (1.0f + erff(x * 0.70710678118654752f));
}

template <bool LN_A, bool GELU_EPI, bool ADD_EPI>
__global__ __launch_bounds__(256) void k_gemm(
    const float* __restrict__ A, int lda,
    const float* __restrict__ W,           // [N][K] row-major
    const float* __restrict__ gamma, const float* __restrict__ beta,
    const float2* __restrict__ stats,
    const float* __restrict__ bias,        // [N] or nullptr
    const float* __restrict__ addsrc, int ldadd,
    float* __restrict__ C, int ldc,
    int Mrows, int K)
{
    __shared__ float As[16][65];
    __shared__ float Ws[16][65];

    const int tid = threadIdx.x;
    const int tx = tid & 15;
    const int ty = tid >> 4;
    const int row0 = blockIdx.y * 64;
    const int col0 = blockIdx.x * 64;
    const int lk = tid & 15;   // k within tile
    const int lr = tid >> 4;   // row/col index base (16 at a time)

    float acc[4][4];
#pragma unroll
    for (int i = 0; i < 4; ++i)
#pragma unroll
        for (int j = 0; j < 4; ++j) acc[i][j] = 0.f;

    for (int kk = 0; kk < K; kk += 16) {
        const int kcol = kk + lk;
#pragma unroll
        for (int it = 0; it < 4; ++it) {
            int r = row0 + lr + it * 16;
            float v = 0.f;
            if (r < Mrows) {
                v = A[(size_t)r * lda + kcol];
                if (LN_A) {
                    float2 st = stats[r];
                    v = (v - st.x) * st.y * gamma[kcol] + beta[kcol];
                }
            }
            As[lk][lr + it * 16] = v;
            int n = col0 + lr + it * 16;
            Ws[lk][lr + it * 16] = W[(size_t)n * K + kcol];
        }
        __syncthreads();
#pragma unroll
        for (int k = 0; k < 16; ++k) {
            float a[4], w[4];
#pragma unroll
            for (int i = 0; i < 4; ++i) a[i] = As[k][ty * 4 + i];
#pragma unroll
            for (int j = 0; j < 4; ++j) w[j] = Ws[k][tx * 4 + j];
#pragma unroll
            for (int i = 0; i < 4; ++i)
#pragma unroll
                for (int j = 0; j < 4; ++j) acc[i][j] += a[i] * w[j];
        }
        __syncthreads();
    }

#pragma unroll
    for (int i = 0; i < 4; ++i) {
        int r = row0 + ty * 4 + i;
        if (r >= Mrows) continue;
#pragma unroll
        for (int j = 0; j < 4; ++j) {
            int n = col0 + tx * 4 + j;
            float c = acc[i][j];
            if (bias) c += bias[n];
            if (GELU_EPI) c = gelu_exact(c);
            if (ADD_EPI) c += addsrc[(size_t)r * ldadd + n];
            C[(size_t)r * ldc + n] = c;
        }
    }
}

// ---------------------------------------------------------------------------
// K3: KtV[bih][d1][d2] = scale * sum_j K[j][d1] * V[j][d2]
// qkv layout: [RTOT][768], K at col 256+h*32+d, V at col 512+h*32+d
// grid = BI*H = 128 blocks x 256 threads; each thread owns 4 outputs
// ---------------------------------------------------------------------------
__global__ __launch_bounds__(256) void k_ktv(const float* __restrict__ qkv,
                                             float* __restrict__ KtV) {
    __shared__ float Ks[8][32];
    __shared__ float Vs[8][32];

    const int bih = blockIdx.x;
    const int bi = bih >> 3;
    const int h  = bih & 7;
    const float* baseK = qkv + (size_t)bi * JJ * NQKV + MM     + h * DH;
    const float* baseV = qkv + (size_t)bi * JJ * NQKV + 2 * MM + h * DH;

    const int t = threadIdx.x;
    const int srow = t >> 5;   // staging row 0..7
    const int scol = t & 31;   // staging col
    const int d2 = t & 31;
    const int d1b = t >> 5;    // d1 base; outputs d1 = d1b + 8p

    float acc[4] = {0.f, 0.f, 0.f, 0.f};

    for (int j0 = 0; j0 < JJ; j0 += 8) {
        int j = j0 + srow;
        float kv = 0.f, vv = 0.f;
        if (j < JJ) {
            kv = baseK[(size_t)j * NQKV + scol];
            vv = baseV[(size_t)j * NQKV + scol];
        }
        Ks[srow][scol] = kv;
        Vs[srow][scol] = vv;
        __syncthreads();
#pragma unroll
        for (int jl = 0; jl < 8; ++jl) {
            float v = Vs[jl][d2];
#pragma unroll
            for (int p = 0; p < 4; ++p) acc[p] += Ks[jl][d1b + 8 * p] * v;
        }
        __syncthreads();
    }

    const float scale = 0.17677669529663687f;  // 1/sqrt(32)
    float* out = KtV + (size_t)bih * DH * DH;
#pragma unroll
    for (int p = 0; p < 4; ++p) out[(d1b + 8 * p) * DH + d2] = scale * acc[p];
}

// ---------------------------------------------------------------------------
// K4: s2[r][m] = woSum[m] * (Q[r] @ KtV[h])[d] + savespace[r][m]
// grid = RTOT blocks x 256 threads (m = h*32+d)
// ---------------------------------------------------------------------------
__global__ __launch_bounds__(256) void k_imv_s2(const float* __restrict__ qkv,
                                                const float* __restrict__ KtV,
                                                const float* __restrict__ woSum,
                                                const float* __restrict__ savespace,
                                                float* __restrict__ s2) {
    __shared__ float q[256];
    const int r = blockIdx.x;
    const int t = threadIdx.x;
    const int bi = r / JJ;

    q[t] = qkv[(size_t)r * NQKV + t];
    __syncthreads();

    const int h = t >> 5;
    const int d = t & 31;
    const float* kv = KtV + (size_t)(bi * HH + h) * DH * DH;
    float acc = 0.f;
#pragma unroll
    for (int dd = 0; dd < DH; ++dd) acc += q[h * DH + dd] * kv[dd * DH + d];

    size_t idx = (size_t)r * MM + t;
    s2[idx] = woSum[t] * acc + savespace[idx];
}

// ---------------------------------------------------------------------------
extern "C" void kernel_launch(void* const* d_in, const int* in_sizes, int n_in,
                              void* d_out, int out_size, void* d_ws, size_t ws_size,
                              hipStream_t stream) {
    const float* savespace = (const float*)d_in[1];
    const float* Wqkv      = (const float*)d_in[2];   // [3][8][32][256] == [768][256]
    const float* Wo        = (const float*)d_in[3];
    const float* ln1_g     = (const float*)d_in[4];
    const float* ln1_b     = (const float*)d_in[5];
    const float* ln2_g     = (const float*)d_in[6];
    const float* ln2_b     = (const float*)d_in[7];
    const float* fc1_w     = (const float*)d_in[8];   // [1024][256]
    const float* fc1_b     = (const float*)d_in[9];
    const float* fc2_w     = (const float*)d_in[10];  // [256][1024]
    const float* fc2_b     = (const float*)d_in[11];
    float* out = (float*)d_out;

    // Workspace layout (floats)
    float* ws = (float*)d_ws;
    float* woSum  = ws;                         // 256
    float* KtV    = woSum  + 256;               // 128*1024 = 131072
    float2* stats1 = (float2*)(KtV + 131072);   // 16400 float2 = 32800 floats
    float2* stats2 = stats1 + RTOT;             // 32800 floats
    float* s2     = (float*)(stats2 + RTOT);    // 4,198,400
    float* bufB   = s2 + (size_t)RTOT * MM;     // max(qkv 12.6M, T 16.8M) = 16,793,600

    float* qkv = bufB;           // [RTOT][768]
    float* T   = bufB;           // [RTOT][1024] (reuses qkv after it is dead)

    // K0: Wo row sums
    k_wosum<<<1, 256, 0, stream>>>(Wo, woSum);

    // K1: LN1 stats on savespace
    k_lnstats<<<RTOT, 256, 0, stream>>>(savespace, stats1);

    // K2: QKV = LN1(savespace) @ Wqkv^T   [16400 x 768], K=256
    {
        dim3 grid(NQKV / 64, (RTOT + 63) / 64);
        k_gemm<true, false, false><<<grid, 256, 0, stream>>>(
            savespace, MM, Wqkv, ln1_g, ln1_b, stats1,
            nullptr, nullptr, 0, qkv, NQKV, RTOT, MM);
    }

    // K3: KtV per (b,i,h), scale folded in
    k_ktv<<<BI * HH, 256, 0, stream>>>(qkv, KtV);

    // K4: s2 = woSum * (Q @ KtV) + savespace
    k_imv_s2<<<RTOT, 256, 0, stream>>>(qkv, KtV, woSum, savespace, s2);

    // K5: LN2 stats on s2
    k_lnstats<<<RTOT, 256, 0, stream>>>(s2, stats2);

    // K6: T = gelu( LN2(s2) @ fc1_w^T + fc1_b )   [16400 x 1024], K=256
    {
        dim3 grid(HID / 64, (RTOT + 63) / 64);
        k_gemm<true, true, false><<<grid, 256, 0, stream>>>(
            s2, MM, fc1_w, ln2_g, ln2_b, stats2,
            fc1_b, nullptr, 0, T, HID, RTOT, MM);
    }

    // K7: out = T @ fc2_w^T + fc2_b + s2   [16400 x 256], K=1024
    {
        dim3 grid(MM / 64, (RTOT + 63) / 64);
        k_gemm<false, false, true><<<grid, 256, 0, stream>>>(
            T, HID, fc2_w, nullptr, nullptr, nullptr,
            fc2_b, s2, MM, out, MM, RTOT, HID);
    }
}

// Round 2
// 277.700 us; speedup vs baseline: 2.8753x; 2.8753x over previous
//
#include <hip/hip_runtime.h>
#include <hip/hip_bf16.h>
#include <math.h>

// Problem constants (B=2, I=8, J=1025, M=256, H=8, Dh=32)
#define BB   2
#define II   8
#define JJ   1025
#define MM   256
#define HH   8
#define DH   32
#define BI   (BB*II)          // 16
#define RTOT (BI*JJ)          // 16400 rows (tokens)
#define NQKV (3*MM)           // 768
#define HID  (4*MM)           // 1024
#define MPAD 16512            // 129 * 128 (M padded to 128-tile multiple)
#define TILE_P 40             // LDS row pitch in bf16 elems (80B -> 2-way bank alias = free)

typedef unsigned short ushort;
typedef __attribute__((ext_vector_type(8))) short short8;   // 8 bf16 (4 VGPRs)
typedef __attribute__((ext_vector_type(4))) float f32x4;    // MFMA acc / 16B loads

__device__ __forceinline__ ushort f2bf(float x) {
    __hip_bfloat16 h = __float2bfloat16(x);
    return *reinterpret_cast<ushort*>(&h);
}
__device__ __forceinline__ float bf2f(ushort u) {
    __hip_bfloat16 h = *reinterpret_cast<__hip_bfloat16*>(&u);
    return __bfloat162float(h);
}
__device__ __forceinline__ float gelu_exact(float x) {
    return 0.5f * x * (1.0f + erff(x * 0.70710678118654752f));
}
__device__ __forceinline__ float block_sum256(float v, float* red, int t) {
    red[t] = v; __syncthreads();
    for (int s = 128; s > 0; s >>= 1) {
        if (t < s) red[t] += red[t + s];
        __syncthreads();
    }
    float r = red[0]; __syncthreads();
    return r;
}

// ---------------------------------------------------------------------------
// K0: woSum[m] = sum_n Wo[m][n]  (one block per row, coalesced)
// ---------------------------------------------------------------------------
__global__ __launch_bounds__(256) void k_wosum(const float* __restrict__ Wo,
                                               float* __restrict__ woSum) {
    __shared__ float red[256];
    int m = blockIdx.x, t = threadIdx.x;
    float s = block_sum256(Wo[m * MM + t], red, t);
    if (t == 0) woSum[m] = s;
}

// ---------------------------------------------------------------------------
// Casts: fp32 -> bf16, and fp32 -> (hi,lo) bf16 split
// ---------------------------------------------------------------------------
__global__ __launch_bounds__(256) void k_cast(const float* __restrict__ src,
                                              ushort* __restrict__ dst, int n) {
    int i = blockIdx.x * 256 + threadIdx.x;
    if (i < n) dst[i] = f2bf(src[i]);
}
__global__ __launch_bounds__(256) void k_split(const float* __restrict__ src,
                                               ushort* __restrict__ hi,
                                               ushort* __restrict__ lo, int n) {
    int i = blockIdx.x * 256 + threadIdx.x;
    if (i < n) {
        float x = src[i];
        ushort h = f2bf(x);
        hi[i] = h;
        lo[i] = f2bf(x - bf2f(h));
    }
}

// ---------------------------------------------------------------------------
// K1: fused LN1 stats + apply + bf16 hi/lo split.  grid = MPAD rows.
// ---------------------------------------------------------------------------
__global__ __launch_bounds__(256) void k_ln1cast(const float* __restrict__ save,
                                                 const float* __restrict__ g1,
                                                 const float* __restrict__ b1,
                                                 ushort* __restrict__ Ah,
                                                 ushort* __restrict__ Al) {
    __shared__ float red[256];
    int r = blockIdx.x, t = threadIdx.x;
    size_t idx = (size_t)r * MM + t;
    if (r >= RTOT) { Ah[idx] = 0; Al[idx] = 0; return; }
    float x = save[idx];
    float mu = block_sum256(x, red, t) * (1.0f / MM);
    float d = x - mu;
    float var = block_sum256(d * d, red, t) * (1.0f / MM);
    float rstd = 1.0f / sqrtf(var + 1e-5f);
    float v = d * rstd * g1[t] + b1[t];
    ushort h = f2bf(v);
    Ah[idx] = h;
    Al[idx] = f2bf(v - bf2f(h));
}

// ---------------------------------------------------------------------------
// MFMA GEMM: C[r][n] = epi( sum_k A[r][k] * W[n][k] ), A,W bf16, 128x128x32
// SPLIT3: A=Ah+Al, W=Wh+Wl -> 3 MFMA products (fp32-equivalent precision)
// 256 threads = 4 waves; wave (wm,wn) owns a 64x64 quadrant = 4x4 MFMA tiles.
// ---------------------------------------------------------------------------
template <bool SPLIT3, bool GELU_EPI, bool ADD_EPI, bool STORE_BF16, bool GUARD_M>
__global__ __launch_bounds__(256) void k_mfma_gemm(
    const ushort* __restrict__ Ah, const ushort* __restrict__ Al,
    const ushort* __restrict__ Wh, const ushort* __restrict__ Wl,
    const float* __restrict__ bias,
    const float* __restrict__ addsrc,
    void* __restrict__ Cout, int ldc,
    int K, int Mrows)
{
    __shared__ ushort sAh[128 * TILE_P];
    __shared__ ushort sBh[128 * TILE_P];
    __shared__ ushort sAl[SPLIT3 ? 128 * TILE_P : 1];
    __shared__ ushort sBl[SPLIT3 ? 128 * TILE_P : 1];

    const int tid  = threadIdx.x;
    const int wave = tid >> 6;
    const int lane = tid & 63;
    const int wm = wave & 1, wn = wave >> 1;
    const int lrow = lane & 15;   // m (A) / n (B) / col (C) within 16-tile
    const int quad = lane >> 4;   // 0..3
    const int row0 = blockIdx.y * 128;
    const int col0 = blockIdx.x * 128;

    f32x4 acc[4][4] = {};

    for (int kk = 0; kk < K; kk += 32) {
        // stage 128x32 bf16 tiles (16B per thread per pass, 2 passes per tile)
#pragma unroll
        for (int it = 0; it < 2; ++it) {
            int lin = it * 256 + tid;
            int r = lin >> 2;
            int c = (lin & 3) * 8;
            *(f32x4*)&sAh[r * TILE_P + c] =
                *(const f32x4*)(Ah + (size_t)(row0 + r) * K + kk + c);
            *(f32x4*)&sBh[r * TILE_P + c] =
                *(const f32x4*)(Wh + (size_t)(col0 + r) * K + kk + c);
            if (SPLIT3) {
                *(f32x4*)&sAl[r * TILE_P + c] =
                    *(const f32x4*)(Al + (size_t)(row0 + r) * K + kk + c);
                *(f32x4*)&sBl[r * TILE_P + c] =
                    *(const f32x4*)(Wl + (size_t)(col0 + r) * K + kk + c);
            }
        }
        __syncthreads();

        short8 fah[4], fbh[4], fal[4], fbl[4];
#pragma unroll
        for (int i = 0; i < 4; ++i) {
            int m = wm * 64 + i * 16 + lrow;
            fah[i] = *(const short8*)&sAh[m * TILE_P + quad * 8];
            if (SPLIT3) fal[i] = *(const short8*)&sAl[m * TILE_P + quad * 8];
        }
#pragma unroll
        for (int j = 0; j < 4; ++j) {
            int n = wn * 64 + j * 16 + lrow;
            fbh[j] = *(const short8*)&sBh[n * TILE_P + quad * 8];
            if (SPLIT3) fbl[j] = *(const short8*)&sBl[n * TILE_P + quad * 8];
        }
#pragma unroll
        for (int i = 0; i < 4; ++i)
#pragma unroll
            for (int j = 0; j < 4; ++j) {
                acc[i][j] = __builtin_amdgcn_mfma_f32_16x16x32_bf16(
                    fah[i], fbh[j], acc[i][j], 0, 0, 0);
                if (SPLIT3) {
                    acc[i][j] = __builtin_amdgcn_mfma_f32_16x16x32_bf16(
                        fal[i], fbh[j], acc[i][j], 0, 0, 0);
                    acc[i][j] = __builtin_amdgcn_mfma_f32_16x16x32_bf16(
                        fah[i], fbl[j], acc[i][j], 0, 0, 0);
                }
            }
        __syncthreads();
    }

    // epilogue: C/D layout col=lane&15, row=quad*4+reg
#pragma unroll
    for (int i = 0; i < 4; ++i) {
#pragma unroll
        for (int j = 0; j < 4; ++j) {
            int ncol = col0 + wn * 64 + j * 16 + lrow;
            float bv = bias ? bias[ncol] : 0.0f;
#pragma unroll
            for (int v = 0; v < 4; ++v) {
                int r = row0 + wm * 64 + i * 16 + quad * 4 + v;
                if (GUARD_M && r >= Mrows) continue;
                float c = acc[i][j][v] + bv;
                if (GELU_EPI) c = gelu_exact(c);
                if (ADD_EPI) c += addsrc[(size_t)r * ldc + ncol];
                if (STORE_BF16) ((ushort*)Cout)[(size_t)r * ldc + ncol] = f2bf(c);
                else            ((float*)Cout)[(size_t)r * ldc + ncol] = c;
            }
        }
    }
}

// ---------------------------------------------------------------------------
// K3: split-J partial KtV.  grid (BI*H, 8).  partial[bih][sp][d1][d2]
// ---------------------------------------------------------------------------
__global__ __launch_bounds__(256) void k_ktv(const float* __restrict__ qkv,
                                             float* __restrict__ partial) {
    __shared__ float Ks[8][32];
    __shared__ float Vs[8][32];

    const int bih = blockIdx.x;
    const int sp  = blockIdx.y;
    const int bi = bih >> 3;
    const int h  = bih & 7;
    const float* baseK = qkv + (size_t)bi * JJ * NQKV + MM     + h * DH;
    const float* baseV = qkv + (size_t)bi * JJ * NQKV + 2 * MM + h * DH;

    const int jbeg = sp * 129;
    const int jend = min(JJ, jbeg + 129);

    const int t = threadIdx.x;
    const int srow = t >> 5;
    const int scol = t & 31;
    const int d2 = t & 31;
    const int d1b = t >> 5;

    float acc[4] = {0.f, 0.f, 0.f, 0.f};

    for (int jb = jbeg; jb < jend; jb += 8) {
        int j = jb + srow;
        float kv = 0.f, vv = 0.f;
        if (j < jend) {
            kv = baseK[(size_t)j * NQKV + scol];
            vv = baseV[(size_t)j * NQKV + scol];
        }
        Ks[srow][scol] = kv;
        Vs[srow][scol] = vv;
        __syncthreads();
#pragma unroll
        for (int jl = 0; jl < 8; ++jl) {
            float v = Vs[jl][d2];
#pragma unroll
            for (int p = 0; p < 4; ++p) acc[p] += Ks[jl][d1b + 8 * p] * v;
        }
        __syncthreads();
    }

    float* out = partial + ((size_t)bih * 8 + sp) * 1024;
#pragma unroll
    for (int p = 0; p < 4; ++p) out[(d1b + 8 * p) * DH + d2] = acc[p];
}

__global__ __launch_bounds__(256) void k_ktv_reduce(const float* __restrict__ partial,
                                                    float* __restrict__ KtV) {
    const int bih = blockIdx.x, t = threadIdx.x;
    const float scale = 0.17677669529663687f;  // 1/sqrt(32)
#pragma unroll
    for (int p = 0; p < 4; ++p) {
        int o = p * 256 + t;
        float s = 0.f;
#pragma unroll
        for (int sp = 0; sp < 8; ++sp) s += partial[((size_t)bih * 8 + sp) * 1024 + o];
        KtV[(size_t)bih * 1024 + o] = scale * s;
    }
}

// ---------------------------------------------------------------------------
// K4: s2 = woSum*(Q@KtV) + savespace; fused LN2 stats+apply -> Hbf (bf16)
// grid = MPAD rows
// ---------------------------------------------------------------------------
__global__ __launch_bounds__(256) void k_imv_s2(const float* __restrict__ qkv,
                                                const float* __restrict__ KtV,
                                                const float* __restrict__ woSum,
                                                const float* __restrict__ save,
                                                const float* __restrict__ g2,
                                                const float* __restrict__ b2,
                                                float* __restrict__ s2,
                                                ushort* __restrict__ Hbf) {
    __shared__ float q[256];
    __shared__ float red[256];
    const int r = blockIdx.x;
    const int t = threadIdx.x;
    size_t idx = (size_t)r * MM + t;
    if (r >= RTOT) { Hbf[idx] = 0; return; }
    const int bi = r / JJ;

    q[t] = qkv[(size_t)r * NQKV + t];
    __syncthreads();

    const int h = t >> 5;
    const int d = t & 31;
    const float* kv = KtV + (size_t)(bi * HH + h) * DH * DH;
    float acc = 0.f;
#pragma unroll
    for (int dd = 0; dd < DH; ++dd) acc += q[h * DH + dd] * kv[dd * DH + d];

    float val = woSum[t] * acc + save[idx];
    s2[idx] = val;

    float mu = block_sum256(val, red, t) * (1.0f / MM);
    float dv = val - mu;
    float var = block_sum256(dv * dv, red, t) * (1.0f / MM);
    float rstd = 1.0f / sqrtf(var + 1e-5f);
    Hbf[idx] = f2bf(dv * rstd * g2[t] + b2[t]);
}

// ---------------------------------------------------------------------------
extern "C" void kernel_launch(void* const* d_in, const int* in_sizes, int n_in,
                              void* d_out, int out_size, void* d_ws, size_t ws_size,
                              hipStream_t stream) {
    const float* savespace = (const float*)d_in[1];
    const float* Wqkv      = (const float*)d_in[2];   // [768][256]
    const float* Wo        = (const float*)d_in[3];
    const float* ln1_g     = (const float*)d_in[4];
    const float* ln1_b     = (const float*)d_in[5];
    const float* ln2_g     = (const float*)d_in[6];
    const float* ln2_b     = (const float*)d_in[7];
    const float* fc1_w     = (const float*)d_in[8];   // [1024][256]
    const float* fc1_b     = (const float*)d_in[9];
    const float* fc2_w     = (const float*)d_in[10];  // [256][1024]
    const float* fc2_b     = (const float*)d_in[11];
    float* out = (float*)d_out;

    // ---- workspace layout (77.4 MB total; aliasing is stream-order-safe) ----
    char* w = (char*)d_ws;
    // region A (50,724,864 B): qkv fp32 [MPAD][768]; later T bf16 [MPAD][1024]
    float*  qkv = (float*)w;
    ushort* T   = (ushort*)w;
    char* cC = w + (size_t)MPAD * NQKV * 4;
    // region C (16,908,288 B): Ah+Al; later partial (4 MB); later s2 (16.79 MB)
    ushort* Ah = (ushort*)cC;
    ushort* Al = (ushort*)(cC + (size_t)MPAD * MM * 2);
    float* partial = (float*)cC;
    float* s2      = (float*)cC;
    char* cH = cC + (size_t)2 * MPAD * MM * 2;
    // region H (8,454,144 B): Hbf bf16 [MPAD][256]
    ushort* Hbf = (ushort*)cH;
    char* cW = cH + (size_t)MPAD * MM * 2;
    // region W (786,432 B): Wh+Wl; later F1bf (512 KB); later F2bf (512 KB)
    ushort* Wh = (ushort*)cW;
    ushort* Wl = (ushort*)(cW + NQKV * MM * 2);
    ushort* F1 = (ushort*)cW;
    ushort* F2 = (ushort*)cW;
    char* cK = cW + 786432;
    float* KtV   = (float*)cK;            // 524,288 B
    float* woSum = (float*)(cK + 524288); // 1,024 B

    // 1) Wo row sums
    k_wosum<<<MM, 256, 0, stream>>>(Wo, woSum);
    // 2) Wqkv -> bf16 hi/lo
    k_split<<<(NQKV * MM + 255) / 256, 256, 0, stream>>>(Wqkv, Wh, Wl, NQKV * MM);
    // 3) LN1 + split savespace
    k_ln1cast<<<MPAD, 256, 0, stream>>>(savespace, ln1_g, ln1_b, Ah, Al);
    // 4) QKV = LN1(save) @ Wqkv^T  (bf16x3, fp32-equivalent)
    {
        dim3 grid(NQKV / 128, MPAD / 128);
        k_mfma_gemm<true, false, false, false, false><<<grid, 256, 0, stream>>>(
            Ah, Al, Wh, Wl, nullptr, nullptr, qkv, NQKV, MM, RTOT);
    }
    // 5) fc1_w -> bf16 (aliases Wh/Wl, now dead)
    k_cast<<<(HID * MM + 255) / 256, 256, 0, stream>>>(fc1_w, F1, HID * MM);
    // 6) KtV partials + reduce
    {
        dim3 grid(BI * HH, 8);
        k_ktv<<<grid, 256, 0, stream>>>(qkv, partial);
    }
    k_ktv_reduce<<<BI * HH, 256, 0, stream>>>(partial, KtV);
    // 7) s2 + fused LN2 -> Hbf
    k_imv_s2<<<MPAD, 256, 0, stream>>>(qkv, KtV, woSum, savespace,
                                       ln2_g, ln2_b, s2, Hbf);
    // 8) T = gelu(LN2(s2) @ fc1_w^T + b1)  -> bf16 (aliases qkv, now dead)
    {
        dim3 grid(HID / 128, MPAD / 128);
        k_mfma_gemm<false, true, false, true, false><<<grid, 256, 0, stream>>>(
            Hbf, nullptr, F1, nullptr, fc1_b, nullptr, T, HID, MM, RTOT);
    }
    // 9) fc2_w -> bf16 (aliases F1, now dead)
    k_cast<<<(MM * HID + 255) / 256, 256, 0, stream>>>(fc2_w, F2, MM * HID);
    // 10) out = T @ fc2_w^T + b2 + s2
    {
        dim3 grid(MM / 128, MPAD / 128);
        k_mfma_gemm<false, false, true, false, true><<<grid, 256, 0, stream>>>(
            T, nullptr, F2, nullptr, fc2_b, s2, out, MM, HID, RTOT);
    }
}

// Round 3
// 236.429 us; speedup vs baseline: 3.3772x; 1.1746x over previous
//
#include <hip/hip_runtime.h>
#include <hip/hip_bf16.h>
#include <math.h>

// Problem constants (B=2, I=8, J=1025, M=256, H=8, Dh=32)
#define BB   2
#define II   8
#define JJ   1025
#define MM   256
#define HH   8
#define DH   32
#define BI   (BB*II)          // 16
#define RTOT (BI*JJ)          // 16400 rows (tokens)
#define NQKV (3*MM)           // 768
#define HID  (4*MM)           // 1024
#define MPAD 16512            // 258 * 64 (rows padded to 64-tile multiple)

// GEMM tile config: 64 rows x 128 cols x 32 k, 256 threads = 4 waves.
// Each wave owns all 64 rows x 32 cols -> 4x2 MFMA frags (acc = 32 VGPRs).
#define BM 64
#define BN 128
#define BK 32
#define LP 40   // LDS row pitch in bf16 (80 B: rows alias banks 2-way = free; 16B-aligned)

typedef unsigned short ushort;
typedef __attribute__((ext_vector_type(8))) short short8;   // 8 bf16 (4 VGPRs)
typedef __attribute__((ext_vector_type(4))) float f32x4;    // MFMA acc / 16B loads

__device__ __forceinline__ ushort f2bf(float x) {
    __hip_bfloat16 h = __float2bfloat16(x);
    return *reinterpret_cast<ushort*>(&h);
}
__device__ __forceinline__ float bf2f(ushort u) {
    __hip_bfloat16 h = *reinterpret_cast<__hip_bfloat16*>(&u);
    return __bfloat162float(h);
}
__device__ __forceinline__ float gelu_exact(float x) {
    return 0.5f * x * (1.0f + erff(x * 0.70710678118654752f));
}
__device__ __forceinline__ float block_sum256(float v, float* red, int t) {
    red[t] = v; __syncthreads();
    for (int s = 128; s > 0; s >>= 1) {
        if (t < s) red[t] += red[t + s];
        __syncthreads();
    }
    float r = red[0]; __syncthreads();
    return r;
}

// ---------------------------------------------------------------------------
// K0: woSum[m] = sum_n Wo[m][n]
// ---------------------------------------------------------------------------
__global__ __launch_bounds__(256) void k_wosum(const float* __restrict__ Wo,
                                               float* __restrict__ woSum) {
    __shared__ float red[256];
    int m = blockIdx.x, t = threadIdx.x;
    float s = block_sum256(Wo[m * MM + t], red, t);
    if (t == 0) woSum[m] = s;
}

// ---------------------------------------------------------------------------
// Fused cast of all three weight matrices to bf16
// ---------------------------------------------------------------------------
#define WQN (NQKV*MM)              // 196608
#define W1N (HID*MM)               // 262144
#define W2N (MM*HID)               // 262144
__global__ __launch_bounds__(256) void k_castw(const float* __restrict__ wq,
                                               const float* __restrict__ w1,
                                               const float* __restrict__ w2,
                                               ushort* __restrict__ dq,
                                               ushort* __restrict__ d1,
                                               ushort* __restrict__ d2) {
    int i = blockIdx.x * 256 + threadIdx.x;
    if (i < WQN) dq[i] = f2bf(wq[i]);
    else if (i < WQN + W1N) d1[i - WQN] = f2bf(w1[i - WQN]);
    else if (i < WQN + W1N + W2N) d2[i - WQN - W1N] = f2bf(w2[i - WQN - W1N]);
}

// ---------------------------------------------------------------------------
// K1: fused LN1 stats + apply -> bf16.  grid = MPAD rows (pads -> 0).
// ---------------------------------------------------------------------------
__global__ __launch_bounds__(256) void k_ln1cast(const float* __restrict__ save,
                                                 const float* __restrict__ g1,
                                                 const float* __restrict__ b1,
                                                 ushort* __restrict__ Ah) {
    __shared__ float red[256];
    int r = blockIdx.x, t = threadIdx.x;
    size_t idx = (size_t)r * MM + t;
    if (r >= RTOT) { Ah[idx] = 0; return; }
    float x = save[idx];
    float mu = block_sum256(x, red, t) * (1.0f / MM);
    float d = x - mu;
    float var = block_sum256(d * d, red, t) * (1.0f / MM);
    float rstd = 1.0f / sqrtf(var + 1e-5f);
    Ah[idx] = f2bf(d * rstd * g1[t] + b1[t]);
}

// ---------------------------------------------------------------------------
// MFMA GEMM: C[r][n] = epi( sum_k A[r][k] * W[n][k] ), bf16 in, 64x128x32,
// register-prefetch double-buffered LDS, one barrier per K-iter.
// ---------------------------------------------------------------------------
template <bool GELU_EPI, bool ADD_EPI, bool STORE_BF16, bool GUARD_M>
__global__ __launch_bounds__(256, 4) void k_mfma_gemm(
    const ushort* __restrict__ A,
    const ushort* __restrict__ W,
    const float* __restrict__ bias,      // [N] or nullptr
    const float* __restrict__ addsrc,    // [Mrows][ldc] or nullptr
    void* __restrict__ Cout, int ldc,
    int K, int Mrows)
{
    __shared__ __align__(16) ushort sA[2][BM * LP];   // 2 x 5120 B
    __shared__ __align__(16) ushort sB[2][BN * LP];   // 2 x 10240 B

    const int tid  = threadIdx.x;
    const int wave = tid >> 6;
    const int lane = tid & 63;
    const int lrow = lane & 15;   // n-col within 16-tile (C/D col) / frag row
    const int quad = lane >> 4;   // 0..3
    const int row0 = blockIdx.y * BM;
    const int col0 = blockIdx.x * BN;

    // staging: A 64x32 = one 16B chunk/thread; B 128x32 = two chunks/thread
    const int ar = tid >> 2;            // 0..63
    const int ac = (tid & 3) * 8;       // k-chunk offset (bf16 elems)
    const int KT = K / BK;

    f32x4 acc[4][2] = {};

    // prologue: load + stage tile 0
    f32x4 ra, rb0, rb1;
    ra  = *(const f32x4*)(A + (size_t)(row0 + ar) * K + ac);
    rb0 = *(const f32x4*)(W + (size_t)(col0 + ar) * K + ac);
    rb1 = *(const f32x4*)(W + (size_t)(col0 + ar + 64) * K + ac);
    *(f32x4*)&sA[0][ar * LP + ac] = ra;
    *(f32x4*)&sB[0][ar * LP + ac] = rb0;
    *(f32x4*)&sB[0][(ar + 64) * LP + ac] = rb1;

    for (int kt = 0; kt < KT; ++kt) {
        __syncthreads();
        const int cur = kt & 1, nxt = cur ^ 1;
        const bool more = (kt + 1 < KT);
        if (more) {
            const int kk = (kt + 1) * BK;
            ra  = *(const f32x4*)(A + (size_t)(row0 + ar) * K + kk + ac);
            rb0 = *(const f32x4*)(W + (size_t)(col0 + ar) * K + kk + ac);
            rb1 = *(const f32x4*)(W + (size_t)(col0 + ar + 64) * K + kk + ac);
        }
        short8 fa[4], fb[2];
#pragma unroll
        for (int i = 0; i < 4; ++i)
            fa[i] = *(const short8*)&sA[cur][(i * 16 + lrow) * LP + quad * 8];
#pragma unroll
        for (int j = 0; j < 2; ++j)
            fb[j] = *(const short8*)&sB[cur][(wave * 32 + j * 16 + lrow) * LP + quad * 8];
#pragma unroll
        for (int i = 0; i < 4; ++i)
#pragma unroll
            for (int j = 0; j < 2; ++j)
                acc[i][j] = __builtin_amdgcn_mfma_f32_16x16x32_bf16(
                    fa[i], fb[j], acc[i][j], 0, 0, 0);
        if (more) {
            *(f32x4*)&sA[nxt][ar * LP + ac] = ra;
            *(f32x4*)&sB[nxt][ar * LP + ac] = rb0;
            *(f32x4*)&sB[nxt][(ar + 64) * LP + ac] = rb1;
        }
    }

    // epilogue: C/D layout col=lane&15, row=quad*4+reg
#pragma unroll
    for (int i = 0; i < 4; ++i) {
#pragma unroll
        for (int j = 0; j < 2; ++j) {
            const int ncol = col0 + wave * 32 + j * 16 + lrow;
            const float bv = bias ? bias[ncol] : 0.0f;
#pragma unroll
            for (int v = 0; v < 4; ++v) {
                const int r = row0 + i * 16 + quad * 4 + v;
                if (GUARD_M && r >= Mrows) continue;
                float c = acc[i][j][v] + bv;
                if (GELU_EPI) c = gelu_exact(c);
                if (ADD_EPI) c += addsrc[(size_t)r * ldc + ncol];
                if (STORE_BF16) ((ushort*)Cout)[(size_t)r * ldc + ncol] = f2bf(c);
                else            ((float*)Cout)[(size_t)r * ldc + ncol] = c;
            }
        }
    }
}

// ---------------------------------------------------------------------------
// K3: split-J partial KtV from bf16 qkv.  grid (BI*H, 8).
// ---------------------------------------------------------------------------
__global__ __launch_bounds__(256) void k_ktv(const ushort* __restrict__ qkv,
                                             float* __restrict__ partial) {
    __shared__ float Ks[8][32];
    __shared__ float Vs[8][32];

    const int bih = blockIdx.x;
    const int sp  = blockIdx.y;
    const int bi = bih >> 3;
    const int h  = bih & 7;
    const ushort* baseK = qkv + (size_t)bi * JJ * NQKV + MM     + h * DH;
    const ushort* baseV = qkv + (size_t)bi * JJ * NQKV + 2 * MM + h * DH;

    const int jbeg = sp * 129;
    const int jend = min(JJ, jbeg + 129);

    const int t = threadIdx.x;
    const int srow = t >> 5;
    const int scol = t & 31;
    const int d2 = t & 31;
    const int d1b = t >> 5;

    float acc[4] = {0.f, 0.f, 0.f, 0.f};

    for (int jb = jbeg; jb < jend; jb += 8) {
        int j = jb + srow;
        float kv = 0.f, vv = 0.f;
        if (j < jend) {
            kv = bf2f(baseK[(size_t)j * NQKV + scol]);
            vv = bf2f(baseV[(size_t)j * NQKV + scol]);
        }
        Ks[srow][scol] = kv;
        Vs[srow][scol] = vv;
        __syncthreads();
#pragma unroll
        for (int jl = 0; jl < 8; ++jl) {
            float v = Vs[jl][d2];
#pragma unroll
            for (int p = 0; p < 4; ++p) acc[p] += Ks[jl][d1b + 8 * p] * v;
        }
        __syncthreads();
    }

    float* out = partial + ((size_t)bih * 8 + sp) * 1024;
#pragma unroll
    for (int p = 0; p < 4; ++p) out[(d1b + 8 * p) * DH + d2] = acc[p];
}

__global__ __launch_bounds__(256) void k_ktv_reduce(const float* __restrict__ partial,
                                                    float* __restrict__ KtV) {
    const int bih = blockIdx.x, t = threadIdx.x;
    const float scale = 0.17677669529663687f;  // 1/sqrt(32)
#pragma unroll
    for (int p = 0; p < 4; ++p) {
        int o = p * 256 + t;
        float s = 0.f;
#pragma unroll
        for (int sp = 0; sp < 8; ++sp) s += partial[((size_t)bih * 8 + sp) * 1024 + o];
        KtV[(size_t)bih * 1024 + o] = scale * s;
    }
}

// ---------------------------------------------------------------------------
// K4: s2 = woSum*(Q@KtV) + savespace; fused LN2 -> Hbf (bf16).  grid = MPAD.
// ---------------------------------------------------------------------------
__global__ __launch_bounds__(256) void k_imv_s2(const ushort* __restrict__ qkv,
                                                const float* __restrict__ KtV,
                                                const float* __restrict__ woSum,
                                                const float* __restrict__ save,
                                                const float* __restrict__ g2,
                                                const float* __restrict__ b2,
                                                float* __restrict__ s2,
                                                ushort* __restrict__ Hbf) {
    __shared__ float q[256];
    __shared__ float red[256];
    const int r = blockIdx.x;
    const int t = threadIdx.x;
    size_t idx = (size_t)r * MM + t;
    if (r >= RTOT) { Hbf[idx] = 0; return; }
    const int bi = r / JJ;

    q[t] = bf2f(qkv[(size_t)r * NQKV + t]);
    __syncthreads();

    const int h = t >> 5;
    const int d = t & 31;
    const float* kv = KtV + (size_t)(bi * HH + h) * DH * DH;
    float acc = 0.f;
#pragma unroll
    for (int dd = 0; dd < DH; ++dd) acc += q[h * DH + dd] * kv[dd * DH + d];

    float val = woSum[t] * acc + save[idx];
    s2[idx] = val;

    float mu = block_sum256(val, red, t) * (1.0f / MM);
    float dv = val - mu;
    float var = block_sum256(dv * dv, red, t) * (1.0f / MM);
    float rstd = 1.0f / sqrtf(var + 1e-5f);
    Hbf[idx] = f2bf(dv * rstd * g2[t] + b2[t]);
}

// ---------------------------------------------------------------------------
extern "C" void kernel_launch(void* const* d_in, const int* in_sizes, int n_in,
                              void* d_out, int out_size, void* d_ws, size_t ws_size,
                              hipStream_t stream) {
    const float* savespace = (const float*)d_in[1];
    const float* Wqkv      = (const float*)d_in[2];   // [768][256]
    const float* Wo        = (const float*)d_in[3];
    const float* ln1_g     = (const float*)d_in[4];
    const float* ln1_b     = (const float*)d_in[5];
    const float* ln2_g     = (const float*)d_in[6];
    const float* ln2_b     = (const float*)d_in[7];
    const float* fc1_w     = (const float*)d_in[8];   // [1024][256]
    const float* fc1_b     = (const float*)d_in[9];
    const float* fc2_w     = (const float*)d_in[10];  // [256][1024]
    const float* fc2_b     = (const float*)d_in[11];
    float* out = (float*)d_out;

    // ---- workspace layout (65.3 MB; stream-order-safe aliasing) ----
    char* w = (char*)d_ws;
    // region0 (33,816,576 B): qkv_bf [MPAD][768] + Ah [MPAD][256]; later T [MPAD][1024]
    ushort* qkv_bf = (ushort*)w;
    ushort* Ah     = (ushort*)(w + (size_t)MPAD * NQKV * 2);   // +25,362,432
    ushort* T      = (ushort*)w;
    char* c1 = w + (size_t)MPAD * HID * 2;                     // 33,816,576
    float* s2 = (float*)c1;                                    // 16,908,288 B
    char* c2 = c1 + (size_t)MPAD * MM * 4;
    ushort* Hbf = (ushort*)c2;                                 // 8,454,144 B
    char* c3 = c2 + (size_t)MPAD * MM * 2;
    float* partial = (float*)c3;                               // 4,194,304 B
    char* c4 = c3 + (size_t)BI * HH * 8 * 1024 * 4;
    float* KtV = (float*)c4;                                   // 524,288 B
    char* c5 = c4 + (size_t)BI * HH * 1024 * 4;
    ushort* WqkvB = (ushort*)c5;                               // 393,216 B
    ushort* F1    = (ushort*)(c5 + WQN * 2);                   // 524,288 B
    ushort* F2    = (ushort*)(c5 + WQN * 2 + W1N * 2);         // 524,288 B
    float* woSum  = (float*)(c5 + WQN * 2 + W1N * 2 + W2N * 2);

    // 1) Wo row sums
    k_wosum<<<MM, 256, 0, stream>>>(Wo, woSum);
    // 2) all weights -> bf16
    k_castw<<<(WQN + W1N + W2N + 255) / 256, 256, 0, stream>>>(
        Wqkv, fc1_w, fc2_w, WqkvB, F1, F2);
    // 3) LN1 + cast
    k_ln1cast<<<MPAD, 256, 0, stream>>>(savespace, ln1_g, ln1_b, Ah);
    // 4) qkv = LN1(save) @ Wqkv^T  -> bf16   grid(6, 258)
    {
        dim3 grid(NQKV / BN, MPAD / BM);
        k_mfma_gemm<false, false, true, false><<<grid, 256, 0, stream>>>(
            Ah, WqkvB, nullptr, nullptr, qkv_bf, NQKV, MM, RTOT);
    }
    // 5) KtV partials + reduce
    {
        dim3 grid(BI * HH, 8);
        k_ktv<<<grid, 256, 0, stream>>>(qkv_bf, partial);
    }
    k_ktv_reduce<<<BI * HH, 256, 0, stream>>>(partial, KtV);
    // 6) s2 + fused LN2 -> Hbf
    k_imv_s2<<<MPAD, 256, 0, stream>>>(qkv_bf, KtV, woSum, savespace,
                                       ln2_g, ln2_b, s2, Hbf);
    // 7) T = gelu(Hbf @ fc1^T + b1) -> bf16   grid(8, 258)  (T overwrites region0)
    {
        dim3 grid(HID / BN, MPAD / BM);
        k_mfma_gemm<true, false, true, false><<<grid, 256, 0, stream>>>(
            Hbf, F1, fc1_b, nullptr, T, HID, MM, RTOT);
    }
    // 8) out = T @ fc2^T + b2 + s2   grid(2, 258)
    {
        dim3 grid(MM / BN, MPAD / BM);
        k_mfma_gemm<false, true, false, true><<<grid, 256, 0, stream>>>(
            T, F2, fc2_b, s2, out, MM, HID, RTOT);
    }
}

// Round 4
// 221.753 us; speedup vs baseline: 3.6007x; 1.0662x over previous
//
#include <hip/hip_runtime.h>
#include <hip/hip_bf16.h>
#include <math.h>

// Problem constants (B=2, I=8, J=1025, M=256, H=8, Dh=32)
#define BB   2
#define II   8
#define JJ   1025
#define MM   256
#define HH   8
#define DH   32
#define BI   (BB*II)          // 16
#define RTOT (BI*JJ)          // 16400 rows (tokens)
#define NQKV (3*MM)           // 768
#define HID  (4*MM)           // 1024
#define MPAD 16512            // 258*64 (rows padded to 64-tile multiple)

// QKV GEMM tile: 64 x 128 x 32, 256 threads = 4 waves
#define BM 64
#define BN 128
#define BK 32
#define LP 40   // LDS pitch bf16 (80 B): 2-way bank alias = free, 16B aligned

#define WQN (NQKV*MM)         // 196608
#define W1N (HID*MM)          // 262144
#define W2N (MM*HID)          // 262144

typedef unsigned short ushort;
typedef __attribute__((ext_vector_type(8))) short short8;    // 8 bf16
typedef __attribute__((ext_vector_type(4))) float f32x4;
typedef __attribute__((ext_vector_type(4))) ushort ushort4v; // 4 bf16 (8 B)

__device__ __forceinline__ ushort f2bf(float x) {
    __hip_bfloat16 h = __float2bfloat16(x);
    return *reinterpret_cast<ushort*>(&h);
}
__device__ __forceinline__ float bf2f(ushort u) {
    __hip_bfloat16 h = *reinterpret_cast<__hip_bfloat16*>(&u);
    return __bfloat162float(h);
}
__device__ __forceinline__ float gelu_exact(float x) {
    return 0.5f * x * (1.0f + erff(x * 0.70710678118654752f));
}
__device__ __forceinline__ float wave_sum(float v) {
#pragma unroll
    for (int off = 32; off > 0; off >>= 1) v += __shfl_xor(v, off);
    return v;
}
__device__ __forceinline__ float block_sum256(float v, float* red, int t) {
    red[t] = v; __syncthreads();
    for (int s = 128; s > 0; s >>= 1) {
        if (t < s) red[t] += red[t + s];
        __syncthreads();
    }
    float r = red[0]; __syncthreads();
    return r;
}

// ---------------------------------------------------------------------------
// K_prep: weight casts + Wo row-sums + KtV zero + Hbf pad-row zero (1 launch)
// grid = 2816 (casts) + 256 (wosum) + 512 (KtV zero) + 112 (Hbf pad) = 3696
// ---------------------------------------------------------------------------
__global__ __launch_bounds__(256) void k_prep(
    const float* __restrict__ wq, const float* __restrict__ w1,
    const float* __restrict__ w2, const float* __restrict__ Wo,
    ushort* __restrict__ dq, ushort* __restrict__ d1, ushort* __restrict__ d2,
    float* __restrict__ woSum, float* __restrict__ KtV,
    ushort* __restrict__ Hbf)
{
    __shared__ float red[256];
    const int gb = blockIdx.x, t = threadIdx.x;
    if (gb < 2816) {
        int i = gb * 256 + t;
        if (i < WQN) dq[i] = f2bf(wq[i]);
        else if (i < WQN + W1N) d1[i - WQN] = f2bf(w1[i - WQN]);
        else d2[i - WQN - W1N] = f2bf(w2[i - WQN - W1N]);
    } else if (gb < 2816 + 256) {
        int m = gb - 2816;
        float s = block_sum256(Wo[m * MM + t], red, t);
        if (t == 0) woSum[m] = s;
    } else if (gb < 2816 + 256 + 512) {
        KtV[(gb - 3072) * 256 + t] = 0.0f;
    } else {
        int row = RTOT + (gb - 3584);
        Hbf[(size_t)row * MM + t] = 0;
    }
}

// ---------------------------------------------------------------------------
// K_ln1: wave-per-row LN1 + bf16 cast. grid = MPAD/4, 4 rows/block.
// ---------------------------------------------------------------------------
__global__ __launch_bounds__(256) void k_ln1(const float* __restrict__ save,
                                             const float* __restrict__ g1,
                                             const float* __restrict__ b1,
                                             ushort* __restrict__ Ah) {
    const int wave = threadIdx.x >> 6, l = threadIdx.x & 63;
    const int row = blockIdx.x * 4 + wave;
    const size_t base = (size_t)row * MM + 4 * l;
    if (row >= RTOT) { ushort4v z = 0; *(ushort4v*)&Ah[base] = z; return; }
    f32x4 v = *(const f32x4*)&save[base];
    float mu = wave_sum(v[0] + v[1] + v[2] + v[3]) * (1.0f / MM);
    f32x4 d;
#pragma unroll
    for (int c = 0; c < 4; ++c) d[c] = v[c] - mu;
    float var = wave_sum(d[0]*d[0] + d[1]*d[1] + d[2]*d[2] + d[3]*d[3]) * (1.0f / MM);
    float rstd = 1.0f / sqrtf(var + 1e-5f);
    f32x4 g = *(const f32x4*)&g1[4 * l];
    f32x4 b = *(const f32x4*)&b1[4 * l];
    ushort4v o;
#pragma unroll
    for (int c = 0; c < 4; ++c) o[c] = f2bf(d[c] * rstd * g[c] + b[c]);
    *(ushort4v*)&Ah[base] = o;
}

// ---------------------------------------------------------------------------
// K_qkv: MFMA GEMM 64x128x32, double-buffered LDS + register prefetch.
// C = A @ W^T, bf16 in/out. grid(6, 258).
// ---------------------------------------------------------------------------
__global__ __launch_bounds__(256, 4) void k_qkv_gemm(
    const ushort* __restrict__ A, const ushort* __restrict__ W,
    ushort* __restrict__ Cout)
{
    __shared__ __align__(16) ushort sA[2][BM * LP];
    __shared__ __align__(16) ushort sB[2][BN * LP];

    const int tid  = threadIdx.x;
    const int wave = tid >> 6;
    const int lane = tid & 63;
    const int lrow = lane & 15;
    const int quad = lane >> 4;
    const int row0 = blockIdx.y * BM;
    const int col0 = blockIdx.x * BN;
    const int ar = tid >> 2;
    const int ac = (tid & 3) * 8;
    const int K = MM, KT = MM / BK;

    f32x4 acc[4][2] = {};

    f32x4 ra, rb0, rb1;
    ra  = *(const f32x4*)(A + (size_t)(row0 + ar) * K + ac);
    rb0 = *(const f32x4*)(W + (size_t)(col0 + ar) * K + ac);
    rb1 = *(const f32x4*)(W + (size_t)(col0 + ar + 64) * K + ac);
    *(f32x4*)&sA[0][ar * LP + ac] = ra;
    *(f32x4*)&sB[0][ar * LP + ac] = rb0;
    *(f32x4*)&sB[0][(ar + 64) * LP + ac] = rb1;

    for (int kt = 0; kt < KT; ++kt) {
        __syncthreads();
        const int cur = kt & 1, nxt = cur ^ 1;
        const bool more = (kt + 1 < KT);
        if (more) {
            const int kk = (kt + 1) * BK;
            ra  = *(const f32x4*)(A + (size_t)(row0 + ar) * K + kk + ac);
            rb0 = *(const f32x4*)(W + (size_t)(col0 + ar) * K + kk + ac);
            rb1 = *(const f32x4*)(W + (size_t)(col0 + ar + 64) * K + kk + ac);
        }
        short8 fa[4], fb[2];
#pragma unroll
        for (int i = 0; i < 4; ++i)
            fa[i] = *(const short8*)&sA[cur][(i * 16 + lrow) * LP + quad * 8];
#pragma unroll
        for (int j = 0; j < 2; ++j)
            fb[j] = *(const short8*)&sB[cur][(wave * 32 + j * 16 + lrow) * LP + quad * 8];
#pragma unroll
        for (int i = 0; i < 4; ++i)
#pragma unroll
            for (int j = 0; j < 2; ++j)
                acc[i][j] = __builtin_amdgcn_mfma_f32_16x16x32_bf16(
                    fa[i], fb[j], acc[i][j], 0, 0, 0);
        if (more) {
            *(f32x4*)&sA[nxt][ar * LP + ac] = ra;
            *(f32x4*)&sB[nxt][ar * LP + ac] = rb0;
            *(f32x4*)&sB[nxt][(ar + 64) * LP + ac] = rb1;
        }
    }
#pragma unroll
    for (int i = 0; i < 4; ++i)
#pragma unroll
        for (int j = 0; j < 2; ++j) {
            const int ncol = col0 + wave * 32 + j * 16 + lrow;
#pragma unroll
            for (int v = 0; v < 4; ++v) {
                const int r = row0 + i * 16 + quad * 4 + v;
                Cout[(size_t)r * NQKV + ncol] = f2bf(acc[i][j][v]);
            }
        }
}

// ---------------------------------------------------------------------------
// K_ktv: split-J partial KtV, scale folded, atomicAdd into zeroed KtV.
// grid (BI*H, 8).
// ---------------------------------------------------------------------------
__global__ __launch_bounds__(256) void k_ktv(const ushort* __restrict__ qkv,
                                             float* __restrict__ KtV) {
    __shared__ float Ks[8][32];
    __shared__ float Vs[8][32];

    const int bih = blockIdx.x;
    const int sp  = blockIdx.y;
    const int bi = bih >> 3;
    const int h  = bih & 7;
    const ushort* baseK = qkv + (size_t)bi * JJ * NQKV + MM     + h * DH;
    const ushort* baseV = qkv + (size_t)bi * JJ * NQKV + 2 * MM + h * DH;

    const int jbeg = sp * 129;
    const int jend = min(JJ, jbeg + 129);

    const int t = threadIdx.x;
    const int srow = t >> 5;
    const int scol = t & 31;
    const int d2 = t & 31;
    const int d1b = t >> 5;

    float acc[4] = {0.f, 0.f, 0.f, 0.f};

    for (int jb = jbeg; jb < jend; jb += 8) {
        int j = jb + srow;
        float kv = 0.f, vv = 0.f;
        if (j < jend) {
            kv = bf2f(baseK[(size_t)j * NQKV + scol]);
            vv = bf2f(baseV[(size_t)j * NQKV + scol]);
        }
        Ks[srow][scol] = kv;
        Vs[srow][scol] = vv;
        __syncthreads();
#pragma unroll
        for (int jl = 0; jl < 8; ++jl) {
            float v = Vs[jl][d2];
#pragma unroll
            for (int p = 0; p < 4; ++p) acc[p] += Ks[jl][d1b + 8 * p] * v;
        }
        __syncthreads();
    }

    const float scale = 0.17677669529663687f;  // 1/sqrt(32)
    float* out = KtV + (size_t)bih * 1024;
#pragma unroll
    for (int p = 0; p < 4; ++p)
        atomicAdd(&out[(d1b + 8 * p) * DH + d2], scale * acc[p]);
}

// ---------------------------------------------------------------------------
// K_imv: s2 = woSum*(Q@KtV) + save; fused LN2 -> Hbf. Wave handles 4 rows
// (shared-bi => KtV loads amortized 4x). grid (65 jchunks, 16 bi).
// ---------------------------------------------------------------------------
__global__ __launch_bounds__(256) void k_imv_s2(const ushort* __restrict__ qkv,
                                                const float* __restrict__ KtV,
                                                const float* __restrict__ woSum,
                                                const float* __restrict__ save,
                                                const float* __restrict__ g2,
                                                const float* __restrict__ b2,
                                                float* __restrict__ s2,
                                                ushort* __restrict__ Hbf) {
    const int tid = threadIdx.x, wave = tid >> 6, l = tid & 63;
    const int jc = blockIdx.x, bi = blockIdx.y;
    const int jbase = jc * 16 + wave * 4;

    float qv[4][4];
#pragma unroll
    for (int rr = 0; rr < 4; ++rr) {
        int j = jbase + rr;
        if (j < JJ) {
            ushort4v q = *(const ushort4v*)&qkv[((size_t)(bi * JJ + j)) * NQKV + 4 * l];
#pragma unroll
            for (int c = 0; c < 4; ++c) qv[rr][c] = bf2f(q[c]);
        } else {
#pragma unroll
            for (int c = 0; c < 4; ++c) qv[rr][c] = 0.f;
        }
    }

    const float* kvb = KtV + (size_t)bi * 8192 + (l >> 3) * 1024 + (l & 7) * 4;
    float acc[4][4] = {};
#pragma unroll
    for (int dd = 0; dd < 32; ++dd) {
        f32x4 kvv = *(const f32x4*)&kvb[dd * 32];
        const int src = (l & 56) + (dd >> 2);
#pragma unroll
        for (int rr = 0; rr < 4; ++rr) {
            float qq = __shfl(qv[rr][dd & 3], src);
#pragma unroll
            for (int c = 0; c < 4; ++c) acc[rr][c] += qq * kvv[c];
        }
    }

    f32x4 ws = *(const f32x4*)&woSum[4 * l];
    f32x4 g  = *(const f32x4*)&g2[4 * l];
    f32x4 b  = *(const f32x4*)&b2[4 * l];

#pragma unroll
    for (int rr = 0; rr < 4; ++rr) {
        int j = jbase + rr;
        bool valid = (j < JJ);
        size_t base = ((size_t)(bi * JJ + (valid ? j : 0))) * MM + 4 * l;
        f32x4 sv = *(const f32x4*)&save[base];
        f32x4 val;
#pragma unroll
        for (int c = 0; c < 4; ++c) val[c] = ws[c] * acc[rr][c] + sv[c];
        float mu = wave_sum(val[0] + val[1] + val[2] + val[3]) * (1.0f / MM);
        f32x4 d;
#pragma unroll
        for (int c = 0; c < 4; ++c) d[c] = val[c] - mu;
        float var = wave_sum(d[0]*d[0] + d[1]*d[1] + d[2]*d[2] + d[3]*d[3]) * (1.0f / MM);
        float rstd = 1.0f / sqrtf(var + 1e-5f);
        if (valid) {
            *(f32x4*)&s2[base] = val;
            ushort4v o;
#pragma unroll
            for (int c = 0; c < 4; ++c) o[c] = f2bf(d[c] * rstd * g[c] + b[c]);
            *(ushort4v*)&Hbf[base] = o;
        }
    }
}

// ---------------------------------------------------------------------------
// K_mlp: fused out = gelu(Hbf @ F1^T + b1) @ F2^T + b2 + s2.
// 32-row blocks, 4 waves; h tile lives in LDS; F1/F2 frags direct from
// global (L2-hot, 1 MB total). grid = MPAD/32 = 516.
// ---------------------------------------------------------------------------
__global__ __launch_bounds__(256, 4) void k_mlp(
    const ushort* __restrict__ Hbf, const ushort* __restrict__ F1B,
    const ushort* __restrict__ F2B, const float* __restrict__ fb1,
    const float* __restrict__ fb2, const float* __restrict__ s2,
    float* __restrict__ out)
{
    __shared__ __align__(16) ushort sA[32 * 264];   // 16.9 KB, pitch 264
    __shared__ __align__(16) ushort sH[32 * 72];    //  4.6 KB, pitch 72

    const int tid = threadIdx.x, wave = tid >> 6, l = tid & 63;
    const int lrow = l & 15, quad = l >> 4;
    const int r0 = blockIdx.x * 32;

    // stage A tile (32 x 256 bf16)
#pragma unroll
    for (int it = 0; it < 4; ++it) {
        int lin = it * 256 + tid;
        int r = lin >> 5, c = (lin & 31) * 8;
        *(f32x4*)&sA[r * 264 + c] = *(const f32x4*)&Hbf[(size_t)(r0 + r) * MM + c];
    }
    __syncthreads();

    f32x4 acc2[2][4] = {};

    for (int cc = 0; cc < 8; ++cc) {
        const int hid0 = cc * 64;
        // GEMM1: h[32 x 16] for n-tile = hid0 + wave*16
        f32x4 acc1[2] = {};
        const int nrow = hid0 + wave * 16 + lrow;
#pragma unroll
        for (int kf = 0; kf < 8; ++kf) {
            short8 fb  = *(const short8*)&F1B[(size_t)nrow * MM + kf * 32 + quad * 8];
            short8 fa0 = *(const short8*)&sA[lrow * 264 + kf * 32 + quad * 8];
            short8 fa1 = *(const short8*)&sA[(16 + lrow) * 264 + kf * 32 + quad * 8];
            acc1[0] = __builtin_amdgcn_mfma_f32_16x16x32_bf16(fa0, fb, acc1[0], 0, 0, 0);
            acc1[1] = __builtin_amdgcn_mfma_f32_16x16x32_bf16(fa1, fb, acc1[1], 0, 0, 0);
        }
        float bv = fb1[nrow];
        __syncthreads();   // prior chunk's GEMM2 reads of sH complete
#pragma unroll
        for (int mt = 0; mt < 2; ++mt)
#pragma unroll
            for (int v = 0; v < 4; ++v) {
                float hv = gelu_exact(acc1[mt][v] + bv);
                sH[(mt * 16 + quad * 4 + v) * 72 + wave * 16 + lrow] = f2bf(hv);
            }
        __syncthreads();
        // GEMM2: acc2 += h(32x64) @ F2chunk^T; wave owns out cols wave*64..+64
#pragma unroll
        for (int kf = 0; kf < 2; ++kf) {
            short8 ha0 = *(const short8*)&sH[lrow * 72 + kf * 32 + quad * 8];
            short8 ha1 = *(const short8*)&sH[(16 + lrow) * 72 + kf * 32 + quad * 8];
#pragma unroll
            for (int jt = 0; jt < 4; ++jt) {
                short8 fb2v = *(const short8*)&F2B[
                    (size_t)(wave * 64 + jt * 16 + lrow) * HID + hid0 + kf * 32 + quad * 8];
                acc2[0][jt] = __builtin_amdgcn_mfma_f32_16x16x32_bf16(ha0, fb2v, acc2[0][jt], 0, 0, 0);
                acc2[1][jt] = __builtin_amdgcn_mfma_f32_16x16x32_bf16(ha1, fb2v, acc2[1][jt], 0, 0, 0);
            }
        }
    }

    // epilogue: + b2 + s2 -> out (fp32)
#pragma unroll
    for (int jt = 0; jt < 4; ++jt) {
        const int col = wave * 64 + jt * 16 + lrow;
        const float bv = fb2[col];
#pragma unroll
        for (int mt = 0; mt < 2; ++mt)
#pragma unroll
            for (int v = 0; v < 4; ++v) {
                const int r = r0 + mt * 16 + quad * 4 + v;
                if (r < RTOT)
                    out[(size_t)r * MM + col] = acc2[mt][jt][v] + bv + s2[(size_t)r * MM + col];
            }
    }
}

// ---------------------------------------------------------------------------
extern "C" void kernel_launch(void* const* d_in, const int* in_sizes, int n_in,
                              void* d_out, int out_size, void* d_ws, size_t ws_size,
                              hipStream_t stream) {
    const float* savespace = (const float*)d_in[1];
    const float* Wqkv      = (const float*)d_in[2];   // [768][256]
    const float* Wo        = (const float*)d_in[3];
    const float* ln1_g     = (const float*)d_in[4];
    const float* ln1_b     = (const float*)d_in[5];
    const float* ln2_g     = (const float*)d_in[6];
    const float* ln2_b     = (const float*)d_in[7];
    const float* fc1_w     = (const float*)d_in[8];   // [1024][256]
    const float* fc1_b     = (const float*)d_in[9];
    const float* fc2_w     = (const float*)d_in[10];  // [256][1024]
    const float* fc2_b     = (const float*)d_in[11];
    float* out = (float*)d_out;

    // ---- workspace layout (~61 MB, no aliasing) ----
    char* w = (char*)d_ws;
    ushort* Ah   = (ushort*)w;                                  //  8,454,144
    ushort* qkv  = (ushort*)(w + 8454144);                      // 25,362,432
    float*  s2   = (float*) (w + 8454144 + 25362432);           // 16,908,288
    ushort* Hbf  = (ushort*)(w + 8454144 + 25362432 + 16908288);//  8,454,144
    char* c4 = w + 8454144 + 25362432 + 16908288 + 8454144;
    ushort* WqkvB = (ushort*)c4;                                //    393,216
    ushort* F1B   = (ushort*)(c4 + WQN * 2);                    //    524,288
    ushort* F2B   = (ushort*)(c4 + WQN * 2 + W1N * 2);          //    524,288
    float*  KtV   = (float*) (c4 + WQN * 2 + W1N * 2 + W2N * 2);//    524,288
    float*  woSum = (float*) (c4 + WQN * 2 + W1N * 2 + W2N * 2 + 524288);

    // 1) prep: weight casts + wosum + KtV zero + Hbf pad zero
    k_prep<<<3696, 256, 0, stream>>>(Wqkv, fc1_w, fc2_w, Wo,
                                     WqkvB, F1B, F2B, woSum, KtV, Hbf);
    // 2) LN1 + cast (wave/row)
    k_ln1<<<MPAD / 4, 256, 0, stream>>>(savespace, ln1_g, ln1_b, Ah);
    // 3) qkv = Ah @ Wqkv^T  grid(6, 258)
    {
        dim3 grid(NQKV / BN, MPAD / BM);
        k_qkv_gemm<<<grid, 256, 0, stream>>>(Ah, WqkvB, qkv);
    }
    // 4) KtV via atomics
    {
        dim3 grid(BI * HH, 8);
        k_ktv<<<grid, 256, 0, stream>>>(qkv, KtV);
    }
    // 5) s2 + fused LN2 -> Hbf  grid(65, 16)
    {
        dim3 grid(65, BI);
        k_imv_s2<<<grid, 256, 0, stream>>>(qkv, KtV, woSum, savespace,
                                           ln2_g, ln2_b, s2, Hbf);
    }
    // 6) fused MLP -> out
    k_mlp<<<MPAD / 32, 256, 0, stream>>>(Hbf, F1B, F2B, fc1_b, fc2_b, s2, out);
}

// Round 5
// 213.926 us; speedup vs baseline: 3.7325x; 1.0366x over previous
//
#include <hip/hip_runtime.h>
#include <hip/hip_bf16.h>
#include <math.h>

// Problem constants (B=2, I=8, J=1025, M=256, H=8, Dh=32)
#define BB   2
#define II   8
#define JJ   1025
#define MM   256
#define HH   8
#define DH   32
#define BI   (BB*II)          // 16
#define RTOT (BI*JJ)          // 16400 rows (tokens)
#define NQKV (3*MM)           // 768
#define HID  (4*MM)           // 1024
#define MPAD 16512            // 258*64 (rows padded to 64-tile multiple)

// QKV GEMM tile: 64 x 128 x 32, 256 threads = 4 waves
#define BM 64
#define BN 128
#define BK 32
#define LP 40   // LDS pitch bf16 (80 B): 2-way bank alias = free, 16B aligned

#define WQN (NQKV*MM)         // 196608
#define W1N (HID*MM)          // 262144
#define W2N (MM*HID)          // 262144

typedef unsigned short ushort;
typedef __attribute__((ext_vector_type(8))) short short8;    // 8 bf16
typedef __attribute__((ext_vector_type(4))) float f32x4;
typedef __attribute__((ext_vector_type(4))) ushort ushort4v; // 4 bf16 (8 B)

__device__ __forceinline__ ushort f2bf(float x) {
    __hip_bfloat16 h = __float2bfloat16(x);
    return *reinterpret_cast<ushort*>(&h);
}
__device__ __forceinline__ float bf2f(ushort u) {
    __hip_bfloat16 h = *reinterpret_cast<__hip_bfloat16*>(&u);
    return __bfloat162float(h);
}
__device__ __forceinline__ float gelu_exact(float x) {
    return 0.5f * x * (1.0f + erff(x * 0.70710678118654752f));
}
__device__ __forceinline__ float wave_sum(float v) {
#pragma unroll
    for (int off = 32; off > 0; off >>= 1) v += __shfl_xor(v, off);
    return v;
}
__device__ __forceinline__ float block_sum256(float v, float* red, int t) {
    red[t] = v; __syncthreads();
    for (int s = 128; s > 0; s >>= 1) {
        if (t < s) red[t] += red[t + s];
        __syncthreads();
    }
    float r = red[0]; __syncthreads();
    return r;
}

// ---------------------------------------------------------------------------
// K_prep: weight casts + Wo row-sums + KtV zero + Hbf pad zero + LN1 (fused)
// grid = 2816 (casts) + 256 (wosum) + 512 (KtV z) + 112 (Hbf pad) + 4128 (LN1)
// ---------------------------------------------------------------------------
__global__ __launch_bounds__(256) void k_prep(
    const float* __restrict__ wq, const float* __restrict__ w1,
    const float* __restrict__ w2, const float* __restrict__ Wo,
    const float* __restrict__ save, const float* __restrict__ g1,
    const float* __restrict__ b1,
    ushort* __restrict__ dq, ushort* __restrict__ d1, ushort* __restrict__ d2,
    float* __restrict__ woSum, float* __restrict__ KtV,
    ushort* __restrict__ Hbf, ushort* __restrict__ Ah)
{
    __shared__ float red[256];
    const int gb = blockIdx.x, t = threadIdx.x;
    if (gb < 2816) {
        int i = gb * 256 + t;
        if (i < WQN) dq[i] = f2bf(wq[i]);
        else if (i < WQN + W1N) d1[i - WQN] = f2bf(w1[i - WQN]);
        else d2[i - WQN - W1N] = f2bf(w2[i - WQN - W1N]);
    } else if (gb < 3072) {
        int m = gb - 2816;
        float s = block_sum256(Wo[m * MM + t], red, t);
        if (t == 0) woSum[m] = s;
    } else if (gb < 3584) {
        KtV[(gb - 3072) * 256 + t] = 0.0f;
    } else if (gb < 3696) {
        int row = RTOT + (gb - 3584);
        Hbf[(size_t)row * MM + t] = 0;
    } else {
        // LN1 + bf16 cast, wave per row
        const int wave = t >> 6, l = t & 63;
        const int row = (gb - 3696) * 4 + wave;
        const size_t base = (size_t)row * MM + 4 * l;
        if (row >= RTOT) { ushort4v z = 0; *(ushort4v*)&Ah[base] = z; return; }
        f32x4 v = *(const f32x4*)&save[base];
        float mu = wave_sum(v[0] + v[1] + v[2] + v[3]) * (1.0f / MM);
        f32x4 d;
#pragma unroll
        for (int c = 0; c < 4; ++c) d[c] = v[c] - mu;
        float var = wave_sum(d[0]*d[0] + d[1]*d[1] + d[2]*d[2] + d[3]*d[3]) * (1.0f / MM);
        float rstd = 1.0f / sqrtf(var + 1e-5f);
        f32x4 g = *(const f32x4*)&g1[4 * l];
        f32x4 b = *(const f32x4*)&b1[4 * l];
        ushort4v o;
#pragma unroll
        for (int c = 0; c < 4; ++c) o[c] = f2bf(d[c] * rstd * g[c] + b[c]);
        *(ushort4v*)&Ah[base] = o;
    }
}

// ---------------------------------------------------------------------------
// K_qkv: MFMA GEMM 64x128x32, double-buffered LDS + register prefetch.
// C = A @ W^T, bf16 in/out. grid(6, 258).
// ---------------------------------------------------------------------------
__global__ __launch_bounds__(256, 4) void k_qkv_gemm(
    const ushort* __restrict__ A, const ushort* __restrict__ W,
    ushort* __restrict__ Cout)
{
    __shared__ __align__(16) ushort sA[2][BM * LP];
    __shared__ __align__(16) ushort sB[2][BN * LP];

    const int tid  = threadIdx.x;
    const int wave = tid >> 6;
    const int lane = tid & 63;
    const int lrow = lane & 15;
    const int quad = lane >> 4;
    const int row0 = blockIdx.y * BM;
    const int col0 = blockIdx.x * BN;
    const int ar = tid >> 2;
    const int ac = (tid & 3) * 8;
    const int K = MM, KT = MM / BK;

    f32x4 acc[4][2] = {};

    f32x4 ra, rb0, rb1;
    ra  = *(const f32x4*)(A + (size_t)(row0 + ar) * K + ac);
    rb0 = *(const f32x4*)(W + (size_t)(col0 + ar) * K + ac);
    rb1 = *(const f32x4*)(W + (size_t)(col0 + ar + 64) * K + ac);
    *(f32x4*)&sA[0][ar * LP + ac] = ra;
    *(f32x4*)&sB[0][ar * LP + ac] = rb0;
    *(f32x4*)&sB[0][(ar + 64) * LP + ac] = rb1;

    for (int kt = 0; kt < KT; ++kt) {
        __syncthreads();
        const int cur = kt & 1, nxt = cur ^ 1;
        const bool more = (kt + 1 < KT);
        if (more) {
            const int kk = (kt + 1) * BK;
            ra  = *(const f32x4*)(A + (size_t)(row0 + ar) * K + kk + ac);
            rb0 = *(const f32x4*)(W + (size_t)(col0 + ar) * K + kk + ac);
            rb1 = *(const f32x4*)(W + (size_t)(col0 + ar + 64) * K + kk + ac);
        }
        short8 fa[4], fb[2];
#pragma unroll
        for (int i = 0; i < 4; ++i)
            fa[i] = *(const short8*)&sA[cur][(i * 16 + lrow) * LP + quad * 8];
#pragma unroll
        for (int j = 0; j < 2; ++j)
            fb[j] = *(const short8*)&sB[cur][(wave * 32 + j * 16 + lrow) * LP + quad * 8];
#pragma unroll
        for (int i = 0; i < 4; ++i)
#pragma unroll
            for (int j = 0; j < 2; ++j)
                acc[i][j] = __builtin_amdgcn_mfma_f32_16x16x32_bf16(
                    fa[i], fb[j], acc[i][j], 0, 0, 0);
        if (more) {
            *(f32x4*)&sA[nxt][ar * LP + ac] = ra;
            *(f32x4*)&sB[nxt][ar * LP + ac] = rb0;
            *(f32x4*)&sB[nxt][(ar + 64) * LP + ac] = rb1;
        }
    }
#pragma unroll
    for (int i = 0; i < 4; ++i)
#pragma unroll
        for (int j = 0; j < 2; ++j) {
            const int ncol = col0 + wave * 32 + j * 16 + lrow;
#pragma unroll
            for (int v = 0; v < 4; ++v) {
                const int r = row0 + i * 16 + quad * 4 + v;
                Cout[(size_t)r * NQKV + ncol] = f2bf(acc[i][j][v]);
            }
        }
}

// ---------------------------------------------------------------------------
// K_ktv: split-J partial KtV, scale folded, atomicAdd into zeroed KtV.
// grid (BI*H, 8).
// ---------------------------------------------------------------------------
__global__ __launch_bounds__(256) void k_ktv(const ushort* __restrict__ qkv,
                                             float* __restrict__ KtV) {
    __shared__ float Ks[8][32];
    __shared__ float Vs[8][32];

    const int bih = blockIdx.x;
    const int sp  = blockIdx.y;
    const int bi = bih >> 3;
    const int h  = bih & 7;
    const ushort* baseK = qkv + (size_t)bi * JJ * NQKV + MM     + h * DH;
    const ushort* baseV = qkv + (size_t)bi * JJ * NQKV + 2 * MM + h * DH;

    const int jbeg = sp * 129;
    const int jend = min(JJ, jbeg + 129);

    const int t = threadIdx.x;
    const int srow = t >> 5;
    const int scol = t & 31;
    const int d2 = t & 31;
    const int d1b = t >> 5;

    float acc[4] = {0.f, 0.f, 0.f, 0.f};

    for (int jb = jbeg; jb < jend; jb += 8) {
        int j = jb + srow;
        float kv = 0.f, vv = 0.f;
        if (j < jend) {
            kv = bf2f(baseK[(size_t)j * NQKV + scol]);
            vv = bf2f(baseV[(size_t)j * NQKV + scol]);
        }
        Ks[srow][scol] = kv;
        Vs[srow][scol] = vv;
        __syncthreads();
#pragma unroll
        for (int jl = 0; jl < 8; ++jl) {
            float v = Vs[jl][d2];
#pragma unroll
            for (int p = 0; p < 4; ++p) acc[p] += Ks[jl][d1b + 8 * p] * v;
        }
        __syncthreads();
    }

    const float scale = 0.17677669529663687f;  // 1/sqrt(32)
    float* out = KtV + (size_t)bih * 1024;
#pragma unroll
    for (int p = 0; p < 4; ++p)
        atomicAdd(&out[(d1b + 8 * p) * DH + d2], scale * acc[p]);
}

// ---------------------------------------------------------------------------
// K_imv: s2 = woSum*(Q@KtV) + save; fused LN2 -> Hbf. Wave handles 4 rows.
// grid (65 jchunks, 16 bi).
// ---------------------------------------------------------------------------
__global__ __launch_bounds__(256) void k_imv_s2(const ushort* __restrict__ qkv,
                                                const float* __restrict__ KtV,
                                                const float* __restrict__ woSum,
                                                const float* __restrict__ save,
                                                const float* __restrict__ g2,
                                                const float* __restrict__ b2,
                                                float* __restrict__ s2,
                                                ushort* __restrict__ Hbf) {
    const int tid = threadIdx.x, wave = tid >> 6, l = tid & 63;
    const int jc = blockIdx.x, bi = blockIdx.y;
    const int jbase = jc * 16 + wave * 4;

    float qv[4][4];
#pragma unroll
    for (int rr = 0; rr < 4; ++rr) {
        int j = jbase + rr;
        if (j < JJ) {
            ushort4v q = *(const ushort4v*)&qkv[((size_t)(bi * JJ + j)) * NQKV + 4 * l];
#pragma unroll
            for (int c = 0; c < 4; ++c) qv[rr][c] = bf2f(q[c]);
        } else {
#pragma unroll
            for (int c = 0; c < 4; ++c) qv[rr][c] = 0.f;
        }
    }

    const float* kvb = KtV + (size_t)bi * 8192 + (l >> 3) * 1024 + (l & 7) * 4;
    float acc[4][4] = {};
#pragma unroll
    for (int dd = 0; dd < 32; ++dd) {
        f32x4 kvv = *(const f32x4*)&kvb[dd * 32];
        const int src = (l & 56) + (dd >> 2);
#pragma unroll
        for (int rr = 0; rr < 4; ++rr) {
            float qq = __shfl(qv[rr][dd & 3], src);
#pragma unroll
            for (int c = 0; c < 4; ++c) acc[rr][c] += qq * kvv[c];
        }
    }

    f32x4 ws = *(const f32x4*)&woSum[4 * l];
    f32x4 g  = *(const f32x4*)&g2[4 * l];
    f32x4 b  = *(const f32x4*)&b2[4 * l];

#pragma unroll
    for (int rr = 0; rr < 4; ++rr) {
        int j = jbase + rr;
        bool valid = (j < JJ);
        size_t base = ((size_t)(bi * JJ + (valid ? j : 0))) * MM + 4 * l;
        f32x4 sv = *(const f32x4*)&save[base];
        f32x4 val;
#pragma unroll
        for (int c = 0; c < 4; ++c) val[c] = ws[c] * acc[rr][c] + sv[c];
        float mu = wave_sum(val[0] + val[1] + val[2] + val[3]) * (1.0f / MM);
        f32x4 d;
#pragma unroll
        for (int c = 0; c < 4; ++c) d[c] = val[c] - mu;
        float var = wave_sum(d[0]*d[0] + d[1]*d[1] + d[2]*d[2] + d[3]*d[3]) * (1.0f / MM);
        float rstd = 1.0f / sqrtf(var + 1e-5f);
        if (valid) {
            *(f32x4*)&s2[base] = val;
            ushort4v o;
#pragma unroll
            for (int c = 0; c < 4; ++c) o[c] = f2bf(d[c] * rstd * g[c] + b[c]);
            *(ushort4v*)&Hbf[base] = o;
        }
    }
}

// ---------------------------------------------------------------------------
// K_mlp v2: fused out = gelu(Hbf @ F1^T + b1) @ F2^T + b2 + s2.
// 32-row blocks, 4 waves, 8 hid-chunks of 64. Software-pipelined weight
// loads: F1 frags for chunk c+1 and F2 frags for chunk c are batch-issued
// BEFORE GEMM1(c), giving each global load a full GEMM phase (+barrier)
// to land. sH double-buffered -> 1 barrier/chunk. grid = MPAD/32 = 516.
// ---------------------------------------------------------------------------
__global__ __launch_bounds__(256, 2) void k_mlp(
    const ushort* __restrict__ Hbf, const ushort* __restrict__ F1B,
    const ushort* __restrict__ F2B, const float* __restrict__ fb1,
    const float* __restrict__ fb2, const float* __restrict__ s2,
    float* __restrict__ out)
{
    __shared__ __align__(16) ushort sA[32 * 264];     // 16.9 KB
    __shared__ __align__(16) ushort sH[2][32 * 72];   // 2 x 4.6 KB

    const int tid = threadIdx.x, wave = tid >> 6, l = tid & 63;
    const int lrow = l & 15, quad = l >> 4;
    const int r0 = blockIdx.x * 32;

    // stage A tile (32 x 256 bf16)
#pragma unroll
    for (int it = 0; it < 4; ++it) {
        int lin = it * 256 + tid;
        int r = lin >> 5, c = (lin & 31) * 8;
        *(f32x4*)&sA[r * 264 + c] = *(const f32x4*)&Hbf[(size_t)(r0 + r) * MM + c];
    }

    // preload per-wave biases for all 8 chunks
    float bv1[8];
#pragma unroll
    for (int cc = 0; cc < 8; ++cc) bv1[cc] = fb1[cc * 64 + wave * 16 + lrow];

    const ushort* f1base = F1B + (size_t)(wave * 16 + lrow) * MM + quad * 8;
    const ushort* f2base = F2B + (size_t)(wave * 64 + lrow) * HID + quad * 8;

    short8 wf1[8];
#pragma unroll
    for (int kf = 0; kf < 8; ++kf)          // F1 batch for chunk 0
        wf1[kf] = *(const short8*)(f1base + (size_t)0 * 64 * MM + kf * 32);

    __syncthreads();   // sA ready

    f32x4 acc2[2][4] = {};

#pragma unroll
    for (int cc = 0; cc < 8; ++cc) {
        // issue next chunk's F1 batch + this chunk's F2 batch (land during GEMMs)
        short8 wf1n[8];
        if (cc < 7) {
#pragma unroll
            for (int kf = 0; kf < 8; ++kf)
                wf1n[kf] = *(const short8*)(f1base + (size_t)(cc + 1) * 64 * MM + kf * 32);
        }
        short8 wf2[8];
#pragma unroll
        for (int jt = 0; jt < 4; ++jt)
#pragma unroll
            for (int kf2 = 0; kf2 < 2; ++kf2)
                wf2[jt * 2 + kf2] = *(const short8*)(
                    f2base + (size_t)(jt * 16) * HID + cc * 64 + kf2 * 32);

        // GEMM1: h[32 x 16] for n-tile = cc*64 + wave*16
        f32x4 acc1[2] = {};
#pragma unroll
        for (int kf = 0; kf < 8; ++kf) {
            short8 fa0 = *(const short8*)&sA[lrow * 264 + kf * 32 + quad * 8];
            short8 fa1 = *(const short8*)&sA[(16 + lrow) * 264 + kf * 32 + quad * 8];
            acc1[0] = __builtin_amdgcn_mfma_f32_16x16x32_bf16(fa0, wf1[kf], acc1[0], 0, 0, 0);
            acc1[1] = __builtin_amdgcn_mfma_f32_16x16x32_bf16(fa1, wf1[kf], acc1[1], 0, 0, 0);
        }
        // gelu -> sH[cc&1]
#pragma unroll
        for (int mt = 0; mt < 2; ++mt)
#pragma unroll
            for (int v = 0; v < 4; ++v) {
                float hv = gelu_exact(acc1[mt][v] + bv1[cc]);
                sH[cc & 1][(mt * 16 + quad * 4 + v) * 72 + wave * 16 + lrow] = f2bf(hv);
            }
        __syncthreads();
        // GEMM2: acc2 += h(32x64) @ F2chunk^T
#pragma unroll
        for (int kf2 = 0; kf2 < 2; ++kf2) {
            short8 ha0 = *(const short8*)&sH[cc & 1][lrow * 72 + kf2 * 32 + quad * 8];
            short8 ha1 = *(const short8*)&sH[cc & 1][(16 + lrow) * 72 + kf2 * 32 + quad * 8];
#pragma unroll
            for (int jt = 0; jt < 4; ++jt) {
                acc2[0][jt] = __builtin_amdgcn_mfma_f32_16x16x32_bf16(ha0, wf2[jt * 2 + kf2], acc2[0][jt], 0, 0, 0);
                acc2[1][jt] = __builtin_amdgcn_mfma_f32_16x16x32_bf16(ha1, wf2[jt * 2 + kf2], acc2[1][jt], 0, 0, 0);
            }
        }
        if (cc < 7) {
#pragma unroll
            for (int kf = 0; kf < 8; ++kf) wf1[kf] = wf1n[kf];
        }
    }

    // epilogue: + b2 + s2 -> out (fp32)
#pragma unroll
    for (int jt = 0; jt < 4; ++jt) {
        const int col = wave * 64 + jt * 16 + lrow;
        const float bv = fb2[col];
#pragma unroll
        for (int mt = 0; mt < 2; ++mt)
#pragma unroll
            for (int v = 0; v < 4; ++v) {
                const int r = r0 + mt * 16 + quad * 4 + v;
                if (r < RTOT)
                    out[(size_t)r * MM + col] = acc2[mt][jt][v] + bv + s2[(size_t)r * MM + col];
            }
    }
}

// ---------------------------------------------------------------------------
extern "C" void kernel_launch(void* const* d_in, const int* in_sizes, int n_in,
                              void* d_out, int out_size, void* d_ws, size_t ws_size,
                              hipStream_t stream) {
    const float* savespace = (const float*)d_in[1];
    const float* Wqkv      = (const float*)d_in[2];   // [768][256]
    const float* Wo        = (const float*)d_in[3];
    const float* ln1_g     = (const float*)d_in[4];
    const float* ln1_b     = (const float*)d_in[5];
    const float* ln2_g     = (const float*)d_in[6];
    const float* ln2_b     = (const float*)d_in[7];
    const float* fc1_w     = (const float*)d_in[8];   // [1024][256]
    const float* fc1_b     = (const float*)d_in[9];
    const float* fc2_w     = (const float*)d_in[10];  // [256][1024]
    const float* fc2_b     = (const float*)d_in[11];
    float* out = (float*)d_out;

    // ---- workspace layout (~61 MB, no aliasing) ----
    char* w = (char*)d_ws;
    ushort* Ah   = (ushort*)w;                                  //  8,454,144
    ushort* qkv  = (ushort*)(w + 8454144);                      // 25,362,432
    float*  s2   = (float*) (w + 8454144 + 25362432);           // 16,908,288
    ushort* Hbf  = (ushort*)(w + 8454144 + 25362432 + 16908288);//  8,454,144
    char* c4 = w + 8454144 + 25362432 + 16908288 + 8454144;
    ushort* WqkvB = (ushort*)c4;                                //    393,216
    ushort* F1B   = (ushort*)(c4 + WQN * 2);                    //    524,288
    ushort* F2B   = (ushort*)(c4 + WQN * 2 + W1N * 2);          //    524,288
    float*  KtV   = (float*) (c4 + WQN * 2 + W1N * 2 + W2N * 2);//    524,288
    float*  woSum = (float*) (c4 + WQN * 2 + W1N * 2 + W2N * 2 + 524288);

    // 1) prep: weight casts + wosum + KtV zero + Hbf pad zero + LN1
    k_prep<<<3696 + MPAD / 4, 256, 0, stream>>>(
        Wqkv, fc1_w, fc2_w, Wo, savespace, ln1_g, ln1_b,
        WqkvB, F1B, F2B, woSum, KtV, Hbf, Ah);
    // 2) qkv = Ah @ Wqkv^T  grid(6, 258)
    {
        dim3 grid(NQKV / BN, MPAD / BM);
        k_qkv_gemm<<<grid, 256, 0, stream>>>(Ah, WqkvB, qkv);
    }
    // 3) KtV via atomics
    {
        dim3 grid(BI * HH, 8);
        k_ktv<<<grid, 256, 0, stream>>>(qkv, KtV);
    }
    // 4) s2 + fused LN2 -> Hbf  grid(65, 16)
    {
        dim3 grid(65, BI);
        k_imv_s2<<<grid, 256, 0, stream>>>(qkv, KtV, woSum, savespace,
                                           ln2_g, ln2_b, s2, Hbf);
    }
    // 5) fused MLP -> out
    k_mlp<<<MPAD / 32, 256, 0, stream>>>(Hbf, F1B, F2B, fc1_b, fc2_b, s2, out);
}